// Round 2
// baseline (2502.333 us; speedup 1.0000x reference)
//
#include <hip/hip_runtime.h>
#include <math.h>

#define TOKENS 16384
#define DMODEL 2048
#define NEXP   256
#define TOPK   8
#define BM     32
#define BK     16
#define NITER  (DMODEL / BK)
#define GRID_MAIN (TOKENS / BM)

#define OFF_IDX  ((size_t)TOKENS * TOPK)
#define OFF_CNT  ((size_t)2 * TOKENS * TOPK)
#define OFF_SCAL (OFF_CNT + NEXP)

// ---- stats: std(ddof=1)/mean, max, min, expected ; sm = 256-float scratch ----
__device__ __forceinline__ void stats_from_counts(float* __restrict__ out,
                                                  float* __restrict__ sm,
                                                  int t, float c) {
    sm[t] = c; __syncthreads();
    for (int s = 128; s > 0; s >>= 1) { if (t < s) sm[t] += sm[t + s]; __syncthreads(); }
    float mean = sm[0] * (1.0f / NEXP);
    __syncthreads();
    float d = c - mean;
    sm[t] = d * d; __syncthreads();
    for (int s = 128; s > 0; s >>= 1) { if (t < s) sm[t] += sm[t + s]; __syncthreads(); }
    float var = sm[0] * (1.0f / (NEXP - 1));
    __syncthreads();
    sm[t] = c; __syncthreads();
    for (int s = 128; s > 0; s >>= 1) { if (t < s) sm[t] = fmaxf(sm[t], sm[t + s]); __syncthreads(); }
    float mx = sm[0]; __syncthreads();
    sm[t] = c; __syncthreads();
    for (int s = 128; s > 0; s >>= 1) { if (t < s) sm[t] = fminf(sm[t], sm[t + s]); __syncthreads(); }
    float mn = sm[0];
    if (t == 0) {
        out[OFF_SCAL + 0] = sqrtf(var) / (mean + 1e-6f);
        out[OFF_SCAL + 1] = mx;
        out[OFF_SCAL + 2] = mn;
        out[OFF_SCAL + 3] = (float)(TOKENS * TOPK) / (float)NEXP;  // 512
    }
}

// ---- transpose w (E x D) -> wT (D x E), LDS-tiled; block 0 zeroes counts+counter ----
__global__ __launch_bounds__(256) void k_prep(const float* __restrict__ w,
                                              float* __restrict__ wT,
                                              float* __restrict__ out,
                                              int* __restrict__ counter) {
    __shared__ float tile[32][33];
    const int bx = blockIdx.x & 63;        // d-tile (64 tiles)
    const int by = blockIdx.x >> 6;        // e-tile (8 tiles)
    const int lx = threadIdx.x & 31;
    const int lyb = threadIdx.x >> 5;      // 0..7
#pragma unroll
    for (int r = 0; r < 4; r++) {
        int ly = lyb + 8 * r;
        tile[ly][lx] = w[(size_t)(by * 32 + ly) * DMODEL + bx * 32 + lx];
    }
    __syncthreads();
#pragma unroll
    for (int r = 0; r < 4; r++) {
        int ly = lyb + 8 * r;
        wT[(size_t)(bx * 32 + ly) * NEXP + by * 32 + lx] = tile[lx][ly];
    }
    if (blockIdx.x == 0) {
        out[OFF_CNT + threadIdx.x] = 0.0f;
        if (counter && threadIdx.x == 0) *counter = 0;
    }
}

// ---- main: GEMM + bias + top-8 + softmax + histogram (+ last-block stats) ----
__global__ __launch_bounds__(256, 2) void k_main(
        const float* __restrict__ x,
        const float* __restrict__ wT,      // (D x E)
        const float* __restrict__ bias,
        float* __restrict__ out,
        int* __restrict__ counter) {
    __shared__ float xT[2][BK][BM];        // 2 x 2 KB   [buf][k][tok]
    __shared__ float wS[2][BK][NEXP];      // 2 x 16 KB  [buf][k][e]
    __shared__ float logits[BM][NEXP];     // 32 KB
    __shared__ float hist[NEXP];           // 1 KB
    __shared__ int   isLast;

    const int tid  = threadIdx.x;
    const int tok0 = blockIdx.x * BM;
    const int ty   = tid >> 5;             // 0..7 -> tokens ty*4..+3
    const int tx   = tid & 31;             // 0..31 -> experts tx*4..+3 and 128+tx*4..+3

    hist[tid] = 0.0f;

    float acc[4][8];
#pragma unroll
    for (int i = 0; i < 4; i++)
#pragma unroll
        for (int j = 0; j < 8; j++) acc[i][j] = 0.0f;

    // staging maps
    const int lx_tok = tid >> 3;           // 0..31
    const int lx_d   = (tid & 7) * 2;      // 0,2,..,14
    const float*  xrow = x + (size_t)(tok0 + lx_tok) * DMODEL + lx_d;
    const float4* wT4  = (const float4*)wT;
    const int wrow0 = tid >> 6;            // 0..3  (row = wrow0 + 4r)
    const int wcol4 = tid & 63;            // float4 col within 256-float row

    float2 xr;
    float4 wr[4];
    auto load_regs = [&](int k0) {
        xr = *(const float2*)(xrow + k0);
        int base = k0 * (NEXP / 4);        // k0*64 float4s
#pragma unroll
        for (int r = 0; r < 4; r++) wr[r] = wT4[base + tid + 256 * r];
    };
    auto store_lds = [&](int b) {
        xT[b][lx_d][lx_tok]     = xr.x;
        xT[b][lx_d + 1][lx_tok] = xr.y;
#pragma unroll
        for (int r = 0; r < 4; r++)
            *(float4*)&wS[b][4 * r + wrow0][wcol4 * 4] = wr[r];
    };
    auto fma_tile = [&](int b) {
#pragma unroll
        for (int k = 0; k < BK; k++) {
            float4 a  = *(const float4*)&xT[b][k][ty * 4];
            float4 b0 = *(const float4*)&wS[b][k][tx * 4];
            float4 b1 = *(const float4*)&wS[b][k][128 + tx * 4];
            float av[4] = {a.x, a.y, a.z, a.w};
            float b0v[4] = {b0.x, b0.y, b0.z, b0.w};
            float b1v[4] = {b1.x, b1.y, b1.z, b1.w};
#pragma unroll
            for (int i = 0; i < 4; i++) {
#pragma unroll
                for (int j = 0; j < 4; j++) {
                    acc[i][j]     = fmaf(av[i], b0v[j], acc[i][j]);
                    acc[i][4 + j] = fmaf(av[i], b1v[j], acc[i][4 + j]);
                }
            }
        }
    };

    // double-buffered K loop, one barrier per chunk
    load_regs(0);
    store_lds(0);
    __syncthreads();
    for (int it = 0; it < NITER; it += 2) {
        load_regs((it + 1) * BK);
        fma_tile(0);
        store_lds(1);
        __syncthreads();
        if (it + 2 < NITER) load_regs((it + 2) * BK);
        fma_tile(1);
        if (it + 2 < NITER) store_lds(0);
        __syncthreads();
    }

    // bias add, write logits to LDS (lane-contiguous float4 stores)
    float4 bb0 = *(const float4*)&bias[tx * 4];
    float4 bb1 = *(const float4*)&bias[128 + tx * 4];
#pragma unroll
    for (int i = 0; i < 4; i++) {
        *(float4*)&logits[ty * 4 + i][tx * 4] =
            make_float4(acc[i][0] + bb0.x, acc[i][1] + bb0.y,
                        acc[i][2] + bb0.z, acc[i][3] + bb0.w);
        *(float4*)&logits[ty * 4 + i][128 + tx * 4] =
            make_float4(acc[i][4] + bb1.x, acc[i][5] + bb1.y,
                        acc[i][6] + bb1.z, acc[i][7] + bb1.w);
    }
    __syncthreads();

    // ---- top-8 per token; each wave handles 8 tokens ----
    const int lane = tid & 63;
    const int wv   = tid >> 6;
    for (int tt = 0; tt < 8; tt++) {
        const int tok = wv * 8 + tt;
        float4 v4 = *(const float4*)&logits[tok][lane * 4];
        float lv[4] = {v4.x, v4.y, v4.z, v4.w};
        int msk = 0xF;
        float topv[TOPK];
        int   topi[TOPK];
#pragma unroll
        for (int r = 0; r < TOPK; r++) {
            float bvv = -INFINITY;
            int   bii = 0x7fffffff;
#pragma unroll
            for (int j = 0; j < 4; j++) {
                if (msk & (1 << j)) {
                    float vv = lv[j];
                    int   ii = lane * 4 + j;
                    if (vv > bvv || (vv == bvv && ii < bii)) { bvv = vv; bii = ii; }
                }
            }
#pragma unroll
            for (int off = 32; off > 0; off >>= 1) {
                float ov = __shfl_xor(bvv, off);
                int   oi = __shfl_xor(bii, off);
                if (ov > bvv || (ov == bvv && oi < bii)) { bvv = ov; bii = oi; }
            }
            topv[r] = bvv;
            topi[r] = bii;
            if ((bii >> 2) == lane) msk &= ~(1 << (bii & 3));
        }
        float m = topv[0];
        float s = 0.0f;
#pragma unroll
        for (int r = 0; r < TOPK; r++) s += expf(topv[r] - m);

        const int gtok = tok0 + tok;
        if (lane < TOPK) {
            out[(size_t)gtok * TOPK + lane] = expf(topv[lane] - m) / s;
        } else if (lane < 2 * TOPK) {
            int r = lane - TOPK;
            out[OFF_IDX + (size_t)gtok * TOPK + r] = (float)topi[r];
            atomicAdd(&hist[topi[r]], 1.0f);
        }
    }
    __syncthreads();
    float hv = hist[tid];
    if (hv != 0.0f) atomicAdd(&out[OFF_CNT + tid], hv);

    // ---- last block computes the stats (device-scope protocol) ----
    if (counter) {
        __syncthreads();   // drain this block's atomics (vmcnt(0) before barrier)
        if (tid == 0) {
            __threadfence();
            int old = atomicAdd(counter, 1);
            isLast = (old == GRID_MAIN - 1) ? 1 : 0;
        }
        __syncthreads();
        if (isLast) {
            __threadfence();
            float c = __hip_atomic_load(&out[OFF_CNT + tid], __ATOMIC_RELAXED,
                                        __HIP_MEMORY_SCOPE_AGENT);
            stats_from_counts(out, &logits[0][0], tid, c);
        }
    }
}

// ---- fallback stats kernel (only if workspace lacks room for the counter) ----
__global__ __launch_bounds__(256) void k_stats(float* __restrict__ out) {
    __shared__ float sm[NEXP];
    stats_from_counts(out, sm, threadIdx.x, out[OFF_CNT + threadIdx.x]);
}

extern "C" void kernel_launch(void* const* d_in, const int* in_sizes, int n_in,
                              void* d_out, int out_size, void* d_ws, size_t ws_size,
                              hipStream_t stream) {
    const float* x    = (const float*)d_in[0];
    const float* w    = (const float*)d_in[1];
    const float* bias = (const float*)d_in[2];
    float* out = (float*)d_out;

    const size_t wT_bytes = (size_t)DMODEL * NEXP * sizeof(float);
    float* wT = (float*)d_ws;
    const bool fused = (ws_size >= wT_bytes + 256);
    int* counter = fused ? (int*)((char*)d_ws + wT_bytes) : nullptr;

    k_prep<<<512, 256, 0, stream>>>(w, wT, out, counter);
    k_main<<<GRID_MAIN, 256, 0, stream>>>(x, wT, bias, out, counter);
    if (!fused) k_stats<<<1, 256, 0, stream>>>(out);
}

// Round 4
// 582.406 us; speedup vs baseline: 4.2965x; 4.2965x over previous
//
#include <hip/hip_runtime.h>
#include <math.h>

#define TOKENS 16384
#define DMODEL 2048
#define NEXP   256
#define TOPK   8
#define BM     32
#define BK     16
#define NCHUNK (DMODEL / BK)       // 128
#define GRID_MAIN (TOKENS / BM)    // 512

#define OFF_IDX  ((size_t)TOKENS * TOPK)
#define OFF_CNT  ((size_t)2 * TOKENS * TOPK)
#define OFF_SCAL (OFF_CNT + NEXP)

// ---- stats: std(ddof=1)/mean, max, min, expected ; sm = 256-float scratch ----
__device__ __forceinline__ void stats_from_counts(float* __restrict__ out,
                                                  float* __restrict__ sm,
                                                  int t, float c) {
    sm[t] = c; __syncthreads();
    for (int s = 128; s > 0; s >>= 1) { if (t < s) sm[t] += sm[t + s]; __syncthreads(); }
    float mean = sm[0] * (1.0f / NEXP);
    __syncthreads();
    float d = c - mean;
    sm[t] = d * d; __syncthreads();
    for (int s = 128; s > 0; s >>= 1) { if (t < s) sm[t] += sm[t + s]; __syncthreads(); }
    float var = sm[0] * (1.0f / (NEXP - 1));
    __syncthreads();
    sm[t] = c; __syncthreads();
    for (int s = 128; s > 0; s >>= 1) { if (t < s) sm[t] = fmaxf(sm[t], sm[t + s]); __syncthreads(); }
    float mx = sm[0]; __syncthreads();
    sm[t] = c; __syncthreads();
    for (int s = 128; s > 0; s >>= 1) { if (t < s) sm[t] = fminf(sm[t], sm[t + s]); __syncthreads(); }
    float mn = sm[0];
    if (t == 0) {
        out[OFF_SCAL + 0] = sqrtf(var) / (mean + 1e-6f);
        out[OFF_SCAL + 1] = mx;
        out[OFF_SCAL + 2] = mn;
        out[OFF_SCAL + 3] = (float)(TOKENS * TOPK) / (float)NEXP;  // 512
    }
}

// ---- transpose w (E x D) -> wT (D x E); block 0 zeroes counts+counter ----
__global__ __launch_bounds__(256) void k_prep(const float* __restrict__ w,
                                              float* __restrict__ wT,
                                              float* __restrict__ out,
                                              int* __restrict__ counter) {
    __shared__ float tile[32][33];
    const int bx = blockIdx.x & 63;        // d-tile (64 tiles)
    const int by = blockIdx.x >> 6;        // e-tile (8 tiles)
    const int lx = threadIdx.x & 31;
    const int lyb = threadIdx.x >> 5;      // 0..7
#pragma unroll
    for (int r = 0; r < 4; r++) {
        int ly = lyb + 8 * r;
        tile[ly][lx] = w[(size_t)(by * 32 + ly) * DMODEL + bx * 32 + lx];
    }
    __syncthreads();
#pragma unroll
    for (int r = 0; r < 4; r++) {
        int ly = lyb + 8 * r;
        wT[(size_t)(bx * 32 + ly) * NEXP + by * 32 + lx] = tile[lx][ly];
    }
    if (blockIdx.x == 0) {
        out[OFF_CNT + threadIdx.x] = 0.0f;
        if (counter && threadIdx.x == 0) *counter = 0;
    }
}

// ---- stage one 16x256 w-chunk (16 KB) into LDS buffer `dst` ----
__device__ __forceinline__ void stage_chunk(const float4* __restrict__ wT4,
                                            float* __restrict__ dst,
                                            int chunk, int tid) {
#if defined(__HIP_DEVICE_COMPILE__) && __has_builtin(__builtin_amdgcn_global_load_lds)
    // async DMA: lds dest = wave-uniform base + lane*16 (no per-lane scatter)
    const float4* g = wT4 + chunk * (BK * NEXP / 4) + tid;
    float* lb = dst + (size_t)(tid & 192) * 4;        // wave-uniform float offset
#pragma unroll
    for (int r = 0; r < 4; r++)
        __builtin_amdgcn_global_load_lds(
            (const __attribute__((address_space(1))) void*)(g + r * 256),
            (__attribute__((address_space(3))) void*)(lb + r * 1024),
            16, 0, 0);
#else
#pragma unroll
    for (int r = 0; r < 4; r++) {
        float4 v = wT4[chunk * (BK * NEXP / 4) + tid + r * 256];
        *(float4*)(dst + (size_t)(tid + r * 256) * 4) = v;
    }
#endif
}

// ---- main: GEMM (wave-uniform tokens, sequential-K) + top-8 + softmax + hist ----
__global__ __launch_bounds__(256, 2) void k_main(
        const float* __restrict__ x,
        const float* __restrict__ wT,      // (D x E)
        const float* __restrict__ bias,
        float* __restrict__ out,
        int* __restrict__ counter) {
    __shared__ float wSf[2][BK][NEXP];     // 32 KB double-buffered w chunks
    __shared__ float hist[NEXP];           // 1 KB
    __shared__ int   isLast;

    const int tid  = threadIdx.x;
    const int lane = tid & 63;
    const int wv   = tid >> 6;             // 0..3; wave owns tokens wv*8..+7
    const int tok0 = blockIdx.x * BM + wv * 8;

    hist[tid] = 0.0f;

    float acc[8][4];                       // 8 tokens x 4 experts (lane*4..+3)
#pragma unroll
    for (int t = 0; t < 8; t++)
#pragma unroll
        for (int e = 0; e < 4; e++) acc[t][e] = 0.0f;

    const float4* wT4 = (const float4*)wT;
    const float*  xb  = x + (size_t)tok0 * DMODEL;

    stage_chunk(wT4, &wSf[0][0][0], 0, tid);
    __syncthreads();                       // drains vmcnt -> buf0 ready

    for (int i = 0; i < NCHUNK; i++) {
        const int b = i & 1;
        if (i + 1 < NCHUNK) stage_chunk(wT4, &wSf[b ^ 1][0][0], i + 1, tid);

        const float* xc = xb + i * BK;
#pragma unroll
        for (int ks = 0; ks < 4; ks++) {
            float4 av[8];                  // wave-uniform addresses: L1 broadcast
#pragma unroll
            for (int t = 0; t < 8; t++)
                av[t] = *(const float4*)(xc + (size_t)t * DMODEL + ks * 4);
#pragma unroll
            for (int kk = 0; kk < 4; kk++) {
                float4 bv = *(const float4*)&wSf[b][ks * 4 + kk][lane * 4];
#pragma unroll
                for (int t = 0; t < 8; t++) {
                    float a = (kk == 0) ? av[t].x : (kk == 1) ? av[t].y
                            : (kk == 2) ? av[t].z : av[t].w;
                    acc[t][0] = fmaf(a, bv.x, acc[t][0]);
                    acc[t][1] = fmaf(a, bv.y, acc[t][1]);
                    acc[t][2] = fmaf(a, bv.z, acc[t][2]);
                    acc[t][3] = fmaf(a, bv.w, acc[t][3]);
                }
            }
        }
        __syncthreads();                   // drains next chunk's DMA; frees buf b
    }

    // ---- top-8 per token, straight from registers (r1-verified semantics) ----
    float4 bb = *(const float4*)&bias[lane * 4];
#pragma unroll
    for (int tt = 0; tt < 8; tt++) {
        float lv[4] = {acc[tt][0] + bb.x, acc[tt][1] + bb.y,
                       acc[tt][2] + bb.z, acc[tt][3] + bb.w};
        int msk = 0xF;
        float topv[TOPK];
        int   topi[TOPK];
#pragma unroll
        for (int r = 0; r < TOPK; r++) {
            float bvv = -INFINITY;
            int   bii = 0x7fffffff;
#pragma unroll
            for (int j = 0; j < 4; j++) {
                if (msk & (1 << j)) {
                    float vv = lv[j];
                    int   ii = lane * 4 + j;
                    if (vv > bvv || (vv == bvv && ii < bii)) { bvv = vv; bii = ii; }
                }
            }
#pragma unroll
            for (int off = 32; off > 0; off >>= 1) {
                float ov = __shfl_xor(bvv, off);
                int   oi = __shfl_xor(bii, off);
                if (ov > bvv || (ov == bvv && oi < bii)) { bvv = ov; bii = oi; }
            }
            topv[r] = bvv;
            topi[r] = bii;
            if ((bii >> 2) == lane) msk &= ~(1 << (bii & 3));
        }
        float m = topv[0];
        float s = 0.0f;
#pragma unroll
        for (int r = 0; r < TOPK; r++) s += expf(topv[r] - m);

        const int gtok = tok0 + tt;
        if (lane < TOPK) {
            out[(size_t)gtok * TOPK + lane] = expf(topv[lane] - m) / s;
        } else if (lane < 2 * TOPK) {
            int r = lane - TOPK;
            out[OFF_IDX + (size_t)gtok * TOPK + r] = (float)topi[r];
            atomicAdd(&hist[topi[r]], 1.0f);
        }
    }
    __syncthreads();
    float hv = hist[tid];
    if (hv != 0.0f) atomicAdd(&out[OFF_CNT + tid], hv);

    // ---- last block computes the stats (r2-verified device-scope protocol) ----
    if (counter) {
        __syncthreads();
        if (tid == 0) {
            __threadfence();
            int old = atomicAdd(counter, 1);
            isLast = (old == GRID_MAIN - 1) ? 1 : 0;
        }
        __syncthreads();
        if (isLast) {
            __threadfence();
            float c = __hip_atomic_load(&out[OFF_CNT + tid], __ATOMIC_RELAXED,
                                        __HIP_MEMORY_SCOPE_AGENT);
            stats_from_counts(out, &wSf[0][0][0], tid, c);
        }
    }
}

// ---- fallback stats kernel (only if workspace lacks room for the counter) ----
__global__ __launch_bounds__(256) void k_stats(float* __restrict__ out) {
    __shared__ float sm[NEXP];
    stats_from_counts(out, sm, threadIdx.x, out[OFF_CNT + threadIdx.x]);
}

extern "C" void kernel_launch(void* const* d_in, const int* in_sizes, int n_in,
                              void* d_out, int out_size, void* d_ws, size_t ws_size,
                              hipStream_t stream) {
    const float* x    = (const float*)d_in[0];
    const float* w    = (const float*)d_in[1];
    const float* bias = (const float*)d_in[2];
    float* out = (float*)d_out;

    const size_t wT_bytes = (size_t)DMODEL * NEXP * sizeof(float);
    float* wT = (float*)d_ws;
    const bool fused = (ws_size >= wT_bytes + 256);
    int* counter = fused ? (int*)((char*)d_ws + wT_bytes) : nullptr;

    k_prep<<<512, 256, 0, stream>>>(w, wT, out, counter);
    k_main<<<GRID_MAIN, 256, 0, stream>>>(x, wT, bias, out, counter);
    if (!fused) k_stats<<<1, 256, 0, stream>>>(out);
}